// Round 1
// baseline (683.492 us; speedup 1.0000x reference)
//
#include <hip/hip_runtime.h>
#include <stdint.h>
#include <stddef.h>

#define T_LEN   2000
#define BATCH   32
#define ROWS    64000      /* B*T */
#define KDIM    1024
#define ADIM    512
#define CCH     32
#define KW      101        /* 2*50+1 */

typedef _Float16 half8_t  __attribute__((ext_vector_type(8)));
typedef float    float4_t __attribute__((ext_vector_type(4)));

__device__ __forceinline__ half8_t pack8(float4_t a, float4_t b) {
    half8_t r;
    r[0] = (_Float16)a.x; r[1] = (_Float16)a.y;
    r[2] = (_Float16)a.z; r[3] = (_Float16)a.w;
    r[4] = (_Float16)b.x; r[5] = (_Float16)b.y;
    r[6] = (_Float16)b.z; r[7] = (_Float16)b.w;
    return r;
}

__device__ __forceinline__ float tanh_fast(float x) {
    float ax = __builtin_fabsf(x);
    ax = fminf(ax, 15.f);
    float e = __expf(2.f * ax);
    float t = 1.f - 2.f / (e + 1.f);
    return (x < 0.f) ? -t : t;
}

/* ---- ws layout (bytes) ---- */
#define OFF_WENCT 0                 /* 512*1024 f16 = 1048576 */
#define OFF_WATTT 1048576           /* 512*32  f16 = 32768   */
#define OFF_CONVA 1081344           /* 64000*32 f16 = 4096000 */
#define OFF_DTERM 5177344           /* 32*512 f32 = 65536    */
#define OFF_EPART 5242880           /* 4*64000 f32 = 1024000 */
#define OFF_CPART 6266880           /* 16*32*1024 f32 = 2097152 -> end 8364032 */

/* W_enc (K=1024,N=512) -> W_enc^T f16 [n][k]; W_att (32,512) -> W_att^T f16 [n][c] */
__global__ __launch_bounds__(256) void k_prep_w(const float* __restrict__ We,
                                                const float* __restrict__ Wa,
                                                _Float16* __restrict__ Wet,
                                                _Float16* __restrict__ Wat) {
    int id = blockIdx.x * 256 + threadIdx.x;
    if (id < ADIM * KDIM) {
        int n = id >> 10, k = id & 1023;
        Wet[id] = (_Float16)We[k * ADIM + n];
    } else {
        int id2 = id - ADIM * KDIM;
        if (id2 < ADIM * CCH) {
            int n = id2 >> 5, c = id2 & 31;
            Wat[id2] = (_Float16)Wa[c * ADIM + n];
        }
    }
}

/* dterm[b][a] = dec_h[b] @ W_dec + b_enc + b_dec + b_att */
__global__ __launch_bounds__(512) void k_dterm(const float* __restrict__ dec_h,
                                               const float* __restrict__ W_dec,
                                               const float* __restrict__ be,
                                               const float* __restrict__ bd,
                                               const float* __restrict__ ba,
                                               float* __restrict__ dterm) {
    __shared__ float dh[KDIM];
    int b = blockIdx.x;
    for (int k = threadIdx.x; k < KDIM; k += 512) dh[k] = dec_h[b * KDIM + k];
    __syncthreads();
    int a = threadIdx.x;  /* 512 threads == ADIM */
    float s = be[a] + bd[a] + ba[a];
    for (int k = 0; k < KDIM; ++k) s += dh[k] * W_dec[k * ADIM + a];
    dterm[b * ADIM + a] = s;
}

/* convA[(b*T+t)*32+c] = sum_j att_prev[b, t+j-50] * conv_w[c][j]   (zero pad) */
__global__ __launch_bounds__(256) void k_conv(const float* __restrict__ att_prev,
                                              const float* __restrict__ conv_w,
                                              _Float16* __restrict__ convA) {
    __shared__ float ap[128 + 100];
    __shared__ float w[CCH * KW];
    int b = blockIdx.y, tt = blockIdx.x;
    int t0 = tt * 128;
    for (int i = threadIdx.x; i < 228; i += 256) {
        int t = t0 - 50 + i;
        ap[i] = (t >= 0 && t < T_LEN) ? att_prev[b * T_LEN + t] : 0.f;
    }
    for (int i = threadIdx.x; i < CCH * KW; i += 256) w[i] = conv_w[i];
    __syncthreads();
    for (int idx = threadIdx.x; idx < 128 * CCH; idx += 256) {
        int tl = idx >> 5, c = idx & 31;
        int t = t0 + tl;
        if (t < T_LEN) {
            float s = 0.f;
            for (int j = 0; j < KW; ++j) s += ap[tl + j] * w[c * KW + j];
            convA[(size_t)(b * T_LEN + t) * CCH + c] = (_Float16)s;
        }
    }
}

/* Fused: e_partial[nc][row] = sum_{a in nc-chunk} tanh(enc@We + conv@Wa + dterm)[row,a] * g[a]
 * grid (4 n-chunks, 500 m-tiles), 256 threads = 4 waves, tile 128x128, wave 64x64. */
__global__ __launch_bounds__(256) void k_gemm_e(const float* __restrict__ enc,
                                                const _Float16* __restrict__ Wet,
                                                const _Float16* __restrict__ convA,
                                                const _Float16* __restrict__ Wat,
                                                const float* __restrict__ dterm,
                                                const float* __restrict__ gvec,
                                                float* __restrict__ epart) {
    __shared__ __attribute__((aligned(16))) _Float16 Ah[128 * 32];
    __shared__ __attribute__((aligned(16))) _Float16 Bh[128 * 32];

    const int tid  = threadIdx.x;
    const int nc   = blockIdx.x;            /* 0..3  */
    const int m0   = blockIdx.y * 128;      /* 0..63872 */
    const int wave = tid >> 6, lane = tid & 63;
    const int quad = lane >> 4, c16 = lane & 15;
    const int wm = (wave >> 1) * 64, wn = (wave & 1) * 64;

    float4_t acc[4][4];
#pragma unroll
    for (int i = 0; i < 4; ++i)
#pragma unroll
        for (int j = 0; j < 4; ++j) acc[i][j] = (float4_t){0.f, 0.f, 0.f, 0.f};

    const int srow = tid >> 1, shalf = tid & 1;
    const float*    aSrc = enc + (size_t)(m0 + srow) * KDIM + shalf * 16;
    const _Float16* bSrc = Wet + (size_t)(nc * 128 + srow) * KDIM + shalf * 16;
    const int ldsOff = srow * 32 + shalf * 16;

    for (int kk = 0; kk < 32; ++kk) {
        const int k0 = kk * 32;
        __syncthreads();
        {
            const float4_t* s = (const float4_t*)(aSrc + k0);
            float4_t v0 = s[0], v1 = s[1], v2 = s[2], v3 = s[3];
            *(half8_t*)&Ah[ldsOff]     = pack8(v0, v1);
            *(half8_t*)&Ah[ldsOff + 8] = pack8(v2, v3);
            const half8_t* bs = (const half8_t*)(bSrc + k0);
            *(half8_t*)&Bh[ldsOff]     = bs[0];
            *(half8_t*)&Bh[ldsOff + 8] = bs[1];
        }
        __syncthreads();
        half8_t af[4], bf[4];
#pragma unroll
        for (int i = 0; i < 4; ++i)
            af[i] = *(const half8_t*)&Ah[(wm + i * 16 + c16) * 32 + quad * 8];
#pragma unroll
        for (int j = 0; j < 4; ++j)
            bf[j] = *(const half8_t*)&Bh[(wn + j * 16 + c16) * 32 + quad * 8];
#pragma unroll
        for (int i = 0; i < 4; ++i)
#pragma unroll
            for (int j = 0; j < 4; ++j)
                acc[i][j] = __builtin_amdgcn_mfma_f32_16x16x32_f16(af[i], bf[j], acc[i][j], 0, 0, 0);
    }

    /* conv extension: one K=32 step; A2 = convA rows (f16), B2 = W_att^T */
    __syncthreads();
    {
        const half8_t* as = (const half8_t*)(convA + (size_t)(m0 + srow) * CCH + shalf * 16);
        *(half8_t*)&Ah[ldsOff]     = as[0];
        *(half8_t*)&Ah[ldsOff + 8] = as[1];
        const half8_t* bs = (const half8_t*)(Wat + (size_t)(nc * 128 + srow) * CCH + shalf * 16);
        *(half8_t*)&Bh[ldsOff]     = bs[0];
        *(half8_t*)&Bh[ldsOff + 8] = bs[1];
    }
    __syncthreads();
    {
        half8_t af[4], bf[4];
#pragma unroll
        for (int i = 0; i < 4; ++i)
            af[i] = *(const half8_t*)&Ah[(wm + i * 16 + c16) * 32 + quad * 8];
#pragma unroll
        for (int j = 0; j < 4; ++j)
            bf[j] = *(const half8_t*)&Bh[(wn + j * 16 + c16) * 32 + quad * 8];
#pragma unroll
        for (int i = 0; i < 4; ++i)
#pragma unroll
            for (int j = 0; j < 4; ++j)
                acc[i][j] = __builtin_amdgcn_mfma_f32_16x16x32_f16(af[i], bf[j], acc[i][j], 0, 0, 0);
    }

    /* epilogue: + dterm, tanh, *g, reduce over this chunk's 128 cols */
    __syncthreads();
    float* e_lds = (float*)Ah;   /* [2][128] */
#pragma unroll
    for (int i = 0; i < 4; ++i) {
        const int rl0 = wm + i * 16 + quad * 4;
#pragma unroll
        for (int r = 0; r < 4; ++r) {
            const int grow = m0 + rl0 + r;
            const int b = grow / T_LEN;
            float s = 0.f;
#pragma unroll
            for (int j = 0; j < 4; ++j) {
                const int col = nc * 128 + wn + j * 16 + c16;
                const float v = acc[i][j][r] + dterm[b * ADIM + col];
                s += tanh_fast(v) * gvec[col];
            }
#pragma unroll
            for (int off = 1; off < 16; off <<= 1) s += __shfl_xor(s, off);
            if (c16 == 0) e_lds[(wave & 1) * 128 + rl0 + r] = s;
        }
    }
    __syncthreads();
    if (tid < 128) epart[nc * ROWS + m0 + tid] = e_lds[tid] + e_lds[128 + tid];
}

/* softmax over T with masking; logit = 2*sum_chunks e_partial, masked -> -2e15 */
__global__ __launch_bounds__(512) void k_softmax(const float* __restrict__ epart,
                                                 const int* __restrict__ enc_len,
                                                 float* __restrict__ attn) {
    __shared__ float ex[T_LEN];
    __shared__ float red[8];
    const int b = blockIdx.x, tid = threadIdx.x;
    const int len = enc_len[b];
    float lmax = -3.4e38f;
    for (int t = tid; t < T_LEN; t += 512) {
        float e = epart[b * T_LEN + t] + epart[ROWS + b * T_LEN + t]
                + epart[2 * ROWS + b * T_LEN + t] + epart[3 * ROWS + b * T_LEN + t];
        float lg = (t < len) ? 2.f * e : -2e15f;
        ex[t] = lg;
        lmax = fmaxf(lmax, lg);
    }
    for (int off = 1; off < 64; off <<= 1) lmax = fmaxf(lmax, __shfl_xor(lmax, off));
    if ((tid & 63) == 0) red[tid >> 6] = lmax;
    __syncthreads();
    const float m = fmaxf(fmaxf(fmaxf(red[0], red[1]), fmaxf(red[2], red[3])),
                          fmaxf(fmaxf(red[4], red[5]), fmaxf(red[6], red[7])));
    float lsum = 0.f;
    for (int t = tid; t < T_LEN; t += 512) {
        float p = __expf(ex[t] - m);
        ex[t] = p;
        lsum += p;
    }
    for (int off = 1; off < 64; off <<= 1) lsum += __shfl_xor(lsum, off);
    __syncthreads();
    if ((tid & 63) == 0) red[tid >> 6] = lsum;
    __syncthreads();
    const float inv = 1.f / (red[0] + red[1] + red[2] + red[3] + red[4] + red[5] + red[6] + red[7]);
    for (int t = tid; t < T_LEN; t += 512) attn[b * T_LEN + t] = ex[t] * inv;
}

/* c partial: cpart[tc][b][d] = sum_{t in chunk} attn[b,t]*enc[b,t,d] */
__global__ __launch_bounds__(256) void k_cpart(const float* __restrict__ attn,
                                               const float* __restrict__ enc,
                                               float* __restrict__ cpart) {
    const int b = blockIdx.y, tc = blockIdx.x, tid = threadIdx.x;
    const int t0 = tc * 125;
    float4_t s = (float4_t){0.f, 0.f, 0.f, 0.f};
    const float4_t* ep = (const float4_t*)(enc + (size_t)b * T_LEN * KDIM) + tid;
    const float* ap = attn + b * T_LEN + t0;
#pragma unroll 5
    for (int tt = 0; tt < 125; ++tt) {
        const float w = ap[tt];
        float4_t v = ep[(size_t)(t0 + tt) * 256];
        s += v * w;
    }
    *(float4_t*)&cpart[(size_t)(tc * BATCH + b) * KDIM + tid * 4] = s;
}

/* out_c[b][o] = b_o[o] + sum_d (sum_p cpart[p][b][d]) * W_o[d][o] */
__global__ __launch_bounds__(512) void k_out(const float* __restrict__ cpart,
                                             const float* __restrict__ W_o,
                                             const float* __restrict__ b_o,
                                             float* __restrict__ out_c) {
    __shared__ float cm[KDIM];
    const int b = blockIdx.x, tid = threadIdx.x;
    for (int d = tid; d < KDIM; d += 512) {
        float s = 0.f;
#pragma unroll
        for (int p = 0; p < 16; ++p) s += cpart[(size_t)(p * BATCH + b) * KDIM + d];
        cm[d] = s;
    }
    __syncthreads();
    for (int o = tid; o < KDIM; o += 512) {
        float s = b_o[o];
        for (int d = 0; d < KDIM; ++d) s += cm[d] * W_o[d * KDIM + o];
        out_c[b * KDIM + o] = s;
    }
}

extern "C" void kernel_launch(void* const* d_in, const int* in_sizes, int n_in,
                              void* d_out, int out_size, void* d_ws, size_t ws_size,
                              hipStream_t stream) {
    const float* enc      = (const float*)d_in[0];
    const int*   enc_len  = (const int*)d_in[1];
    const float* dec_h    = (const float*)d_in[2];
    const float* att_prev = (const float*)d_in[3];
    const float* W_enc    = (const float*)d_in[4];
    const float* b_enc    = (const float*)d_in[5];
    const float* W_dec    = (const float*)d_in[6];
    const float* b_dec    = (const float*)d_in[7];
    const float* W_att    = (const float*)d_in[8];
    const float* b_att    = (const float*)d_in[9];
    const float* conv_w   = (const float*)d_in[10];
    const float* gvec     = (const float*)d_in[11];
    const float* W_o      = (const float*)d_in[12];
    const float* b_o      = (const float*)d_in[13];

    float* out_c    = (float*)d_out;           /* 32*1024 */
    float* out_attn = out_c + BATCH * KDIM;    /* 32*2000 */

    char* ws = (char*)d_ws;
    _Float16* Wet   = (_Float16*)(ws + OFF_WENCT);
    _Float16* Wat   = (_Float16*)(ws + OFF_WATTT);
    _Float16* convA = (_Float16*)(ws + OFF_CONVA);
    float*    dterm = (float*)(ws + OFF_DTERM);
    float*    epart = (float*)(ws + OFF_EPART);
    float*    cpart = (float*)(ws + OFF_CPART);

    k_prep_w<<<2112, 256, 0, stream>>>(W_enc, W_att, Wet, Wat);
    k_dterm<<<BATCH, 512, 0, stream>>>(dec_h, W_dec, b_enc, b_dec, b_att, dterm);
    k_conv<<<dim3(16, BATCH), 256, 0, stream>>>(att_prev, conv_w, convA);
    k_gemm_e<<<dim3(4, 500), 256, 0, stream>>>(enc, Wet, convA, Wat, dterm, gvec, epart);
    k_softmax<<<BATCH, 512, 0, stream>>>(epart, enc_len, out_attn);
    k_cpart<<<dim3(16, BATCH), 256, 0, stream>>>(out_attn, enc, cpart);
    k_out<<<BATCH, 512, 0, stream>>>(cpart, W_o, b_o, out_c);
}

// Round 2
// 627.996 us; speedup vs baseline: 1.0884x; 1.0884x over previous
//
#include <hip/hip_runtime.h>
#include <stdint.h>
#include <stddef.h>

#define T_LEN   2000
#define BATCH   32
#define ROWS    64000      /* B*T */
#define KDIM    1024
#define ADIM    512
#define CCH     32
#define KW      101        /* 2*50+1 */
#define PADA    40         /* A-tile LDS row stride in f16 (pad 32->40) */

typedef _Float16 half8_t  __attribute__((ext_vector_type(8)));
typedef float    float4_t __attribute__((ext_vector_type(4)));

__device__ __forceinline__ half8_t pack8(float4_t a, float4_t b) {
    half8_t r;
    r[0] = (_Float16)a.x; r[1] = (_Float16)a.y;
    r[2] = (_Float16)a.z; r[3] = (_Float16)a.w;
    r[4] = (_Float16)b.x; r[5] = (_Float16)b.y;
    r[6] = (_Float16)b.z; r[7] = (_Float16)b.w;
    return r;
}

__device__ __forceinline__ float tanh_fast(float x) {
    float ax = __builtin_fabsf(x);
    ax = fminf(ax, 15.f);
    float e = __expf(2.f * ax);
    float t = 1.f - 2.f / (e + 1.f);
    return (x < 0.f) ? -t : t;
}

/* async global->LDS, 16B per lane; LDS dest must be wave-uniform base + lane*16 */
__device__ __forceinline__ void glds16(const void* g, void* l) {
    __builtin_amdgcn_global_load_lds((const __attribute__((address_space(1))) uint32_t*)g,
                                     (__attribute__((address_space(3))) uint32_t*)l,
                                     16, 0, 0);
}

/* ---- ws layout (bytes) ---- */
#define OFF_WENCT 0                 /* 512*1024 f16 = 1048576 */
#define OFF_WATTT 1048576           /* 512*32  f16 = 32768   */
#define OFF_CONVA 1081344           /* 64000*32 f16 = 4096000 */
#define OFF_DTERM 5177344           /* 32*512 f32 = 65536    */
#define OFF_EPART 5242880           /* 64000 f32 = 256000    */
#define OFF_CPART 5498880           /* 16*32*1024 f32 = 2097152 -> end 7596032 */

/* W_enc [k=1024][n=512] -> Wet f16 [n][k], coalesced LDS tile transpose */
__global__ __launch_bounds__(256) void k_prep_we(const float* __restrict__ We,
                                                 _Float16* __restrict__ Wet) {
    __shared__ float tile[32][33];
    const int k0 = blockIdx.x * 32, n0 = blockIdx.y * 32;
    const int tx = threadIdx.x & 31, ty = threadIdx.x >> 5;   /* ty 0..7 */
#pragma unroll
    for (int i = 0; i < 4; ++i)
        tile[ty + i * 8][tx] = We[(size_t)(k0 + ty + i * 8) * ADIM + n0 + tx];
    __syncthreads();
#pragma unroll
    for (int i = 0; i < 4; ++i)
        Wet[(size_t)(n0 + ty + i * 8) * KDIM + k0 + tx] = (_Float16)tile[tx][ty + i * 8];
}

/* W_att [c=32][n=512] -> Wat f16 [n][c] (tiny) */
__global__ __launch_bounds__(512) void k_prep_wat(const float* __restrict__ Wa,
                                                  _Float16* __restrict__ Wat) {
    const int n = threadIdx.x;
#pragma unroll
    for (int c = 0; c < CCH; ++c)
        Wat[n * CCH + c] = (_Float16)Wa[c * ADIM + n];
}

/* dterm[b][a] = dec_h[b] @ W_dec + b_enc + b_dec + b_att ; grid (32,4) x 256 */
__global__ __launch_bounds__(256) void k_dterm(const float* __restrict__ dec_h,
                                               const float* __restrict__ W_dec,
                                               const float* __restrict__ be,
                                               const float* __restrict__ bd,
                                               const float* __restrict__ ba,
                                               float* __restrict__ dterm) {
    __shared__ float dh[KDIM];
    __shared__ float part[256];
    const int b = blockIdx.x, a0 = blockIdx.y * 128, tid = threadIdx.x;
#pragma unroll
    for (int i = 0; i < 4; ++i) dh[tid + i * 256] = dec_h[b * KDIM + tid + i * 256];
    __syncthreads();
    const int a = a0 + (tid & 127), kh = (tid >> 7) * 512;
    float s = 0.f;
#pragma unroll 8
    for (int k = 0; k < 512; ++k) s += dh[kh + k] * W_dec[(size_t)(kh + k) * ADIM + a];
    part[tid] = s;
    __syncthreads();
    if (tid < 128) {
        const int aa = a0 + tid;
        dterm[b * ADIM + aa] = part[tid] + part[tid + 128] + be[aa] + bd[aa] + ba[aa];
    }
}

/* convA[(b*T+t)*32+c] = sum_j att_prev[b, t+j-50] * conv_w[c][j]   (zero pad) */
__global__ __launch_bounds__(256) void k_conv(const float* __restrict__ att_prev,
                                              const float* __restrict__ conv_w,
                                              _Float16* __restrict__ convA) {
    __shared__ float ap[128 + 100];
    __shared__ float w[CCH * KW];
    int b = blockIdx.y, tt = blockIdx.x;
    int t0 = tt * 128;
    for (int i = threadIdx.x; i < 228; i += 256) {
        int t = t0 - 50 + i;
        ap[i] = (t >= 0 && t < T_LEN) ? att_prev[b * T_LEN + t] : 0.f;
    }
    for (int i = threadIdx.x; i < CCH * KW; i += 256) w[i] = conv_w[i];
    __syncthreads();
    for (int idx = threadIdx.x; idx < 128 * CCH; idx += 256) {
        int tl = idx >> 5, c = idx & 31;
        int t = t0 + tl;
        if (t < T_LEN) {
            float s = 0.f;
#pragma unroll
            for (int j = 0; j < KW; ++j) s += ap[tl + j] * w[c * KW + j];
            convA[(size_t)(b * T_LEN + t) * CCH + c] = (_Float16)s;
        }
    }
}

/* Fused GEMM+tanh+dot: epart[row] = sum_a tanh(enc@We + conv@Wa + dterm)[row,a]*g[a]
 * grid 500 m-tiles, 512 threads = 8 waves, tile 128x512 (full N), wave 64x128. */
__global__ __launch_bounds__(512, 1) void k_gemm_e(const float* __restrict__ enc,
                                                   const _Float16* __restrict__ Wet,
                                                   const _Float16* __restrict__ convA,
                                                   const _Float16* __restrict__ Wat,
                                                   const float* __restrict__ dterm,
                                                   const float* __restrict__ gvec,
                                                   float* __restrict__ epart) {
    __shared__ __attribute__((aligned(16))) _Float16 Ah[128 * PADA];  /* 10 KB */
    __shared__ __attribute__((aligned(16))) _Float16 Bh[512 * 32];    /* 32 KB */

    const int tid  = threadIdx.x;
    const int m0   = blockIdx.x * 128;
    const int wave = tid >> 6, lane = tid & 63;
    const int quad = lane >> 4, c16 = lane & 15;
    const int wm = (wave >> 2) * 64, wn = (wave & 3) * 128;

    float4_t acc[4][8];
#pragma unroll
    for (int i = 0; i < 4; ++i)
#pragma unroll
        for (int j = 0; j < 8; ++j) acc[i][j] = (float4_t){0.f, 0.f, 0.f, 0.f};

    /* A staging role: 4 threads per row, 8 f32 each */
    const int arow = tid >> 2, aseg = tid & 3;
    const float* aBase = enc + (size_t)(m0 + arow) * KDIM + aseg * 8;
    /* B glds role: per wave, 4 issues x 64 lanes x 16B, contiguous LDS */
    const int bl4 = lane >> 2, bseg = lane & 3;

    /* prefetch A for kk=0 */
    float4_t pa0 = ((const float4_t*)aBase)[0];
    float4_t pa1 = ((const float4_t*)aBase)[1];

    for (int kk = 0; kk < 32; ++kk) {
        const int k0 = kk * 32;
        __syncthreads();
        /* stage A (f32->f16) from prefetch regs */
        *(half8_t*)&Ah[arow * PADA + aseg * 8] = pack8(pa0, pa1);
        /* stage B via async global->LDS (f16, L2-resident) */
#pragma unroll
        for (int p = 0; p < 4; ++p) {
            const int nb = wave * 64 + p * 16 + bl4;
            glds16(Wet + (size_t)nb * KDIM + k0 + bseg * 8, &Bh[nb * 32 + bseg * 8]);
        }
        __syncthreads();
        /* prefetch next A tile — overlaps the MFMA phase below */
        {
            const int kn = (kk < 31) ? (k0 + 32) : k0;
            pa0 = ((const float4_t*)(aBase + kn))[0];
            pa1 = ((const float4_t*)(aBase + kn))[1];
        }
        half8_t af[4], bf[8];
#pragma unroll
        for (int i = 0; i < 4; ++i)
            af[i] = *(const half8_t*)&Ah[(wm + i * 16 + c16) * PADA + quad * 8];
#pragma unroll
        for (int j = 0; j < 8; ++j)
            bf[j] = *(const half8_t*)&Bh[(wn + j * 16 + c16) * 32 + quad * 8];
#pragma unroll
        for (int i = 0; i < 4; ++i)
#pragma unroll
            for (int j = 0; j < 8; ++j)
                acc[i][j] = __builtin_amdgcn_mfma_f32_16x16x32_f16(af[i], bf[j], acc[i][j], 0, 0, 0);
    }

    /* conv extension: one K=32 step; A2 = convA rows (f16), B2 = Wat */
    __syncthreads();
    *(half8_t*)&Ah[arow * PADA + aseg * 8] =
        *(const half8_t*)(convA + (size_t)(m0 + arow) * CCH + aseg * 8);
    {
        const half8_t* bs = (const half8_t*)(Wat + tid * CCH);
#pragma unroll
        for (int s4 = 0; s4 < 4; ++s4) *(half8_t*)&Bh[tid * 32 + s4 * 8] = bs[s4];
    }
    __syncthreads();
    {
        half8_t af[4], bf[8];
#pragma unroll
        for (int i = 0; i < 4; ++i)
            af[i] = *(const half8_t*)&Ah[(wm + i * 16 + c16) * PADA + quad * 8];
#pragma unroll
        for (int j = 0; j < 8; ++j)
            bf[j] = *(const half8_t*)&Bh[(wn + j * 16 + c16) * 32 + quad * 8];
#pragma unroll
        for (int i = 0; i < 4; ++i)
#pragma unroll
            for (int j = 0; j < 8; ++j)
                acc[i][j] = __builtin_amdgcn_mfma_f32_16x16x32_f16(af[i], bf[j], acc[i][j], 0, 0, 0);
    }

    /* epilogue: + dterm, tanh, *g, reduce 128 cols in-wave, combine 4 n-waves */
    __syncthreads();
    float* e_lds = (float*)Ah;   /* [128][4] floats = 2 KB */
#pragma unroll
    for (int i = 0; i < 4; ++i) {
        const int rl0 = wm + i * 16 + quad * 4;
#pragma unroll
        for (int r = 0; r < 4; ++r) {
            const int grow = m0 + rl0 + r;
            const int b = grow / T_LEN;
            float s = 0.f;
#pragma unroll
            for (int j = 0; j < 8; ++j) {
                const int col = wn + j * 16 + c16;
                const float v = acc[i][j][r] + dterm[b * ADIM + col];
                s += tanh_fast(v) * gvec[col];
            }
#pragma unroll
            for (int off = 1; off < 16; off <<= 1) s += __shfl_xor(s, off);
            if (c16 == 0) e_lds[(rl0 + r) * 4 + (wave & 3)] = s;
        }
    }
    __syncthreads();
    if (tid < 128) {
        float4_t q = ((const float4_t*)e_lds)[tid];
        epart[m0 + tid] = q.x + q.y + q.z + q.w;
    }
}

/* softmax over T with masking; logit = 2*epart, masked -> -2e15 */
__global__ __launch_bounds__(512) void k_softmax(const float* __restrict__ epart,
                                                 const int* __restrict__ enc_len,
                                                 float* __restrict__ attn) {
    __shared__ float ex[T_LEN];
    __shared__ float red[8];
    const int b = blockIdx.x, tid = threadIdx.x;
    const int len = enc_len[b];
    float lmax = -3.4e38f;
    for (int t = tid; t < T_LEN; t += 512) {
        float lg = (t < len) ? 2.f * epart[b * T_LEN + t] : -2e15f;
        ex[t] = lg;
        lmax = fmaxf(lmax, lg);
    }
    for (int off = 1; off < 64; off <<= 1) lmax = fmaxf(lmax, __shfl_xor(lmax, off));
    if ((tid & 63) == 0) red[tid >> 6] = lmax;
    __syncthreads();
    const float m = fmaxf(fmaxf(fmaxf(red[0], red[1]), fmaxf(red[2], red[3])),
                          fmaxf(fmaxf(red[4], red[5]), fmaxf(red[6], red[7])));
    float lsum = 0.f;
    for (int t = tid; t < T_LEN; t += 512) {
        float p = __expf(ex[t] - m);
        ex[t] = p;
        lsum += p;
    }
    for (int off = 1; off < 64; off <<= 1) lsum += __shfl_xor(lsum, off);
    __syncthreads();
    if ((tid & 63) == 0) red[tid >> 6] = lsum;
    __syncthreads();
    const float inv = 1.f / (red[0] + red[1] + red[2] + red[3] + red[4] + red[5] + red[6] + red[7]);
    for (int t = tid; t < T_LEN; t += 512) attn[b * T_LEN + t] = ex[t] * inv;
}

/* c partial: cpart[tc][b][d] = sum_{t in chunk} attn[b,t]*enc[b,t,d] */
__global__ __launch_bounds__(256) void k_cpart(const float* __restrict__ attn,
                                               const float* __restrict__ enc,
                                               float* __restrict__ cpart) {
    const int b = blockIdx.y, tc = blockIdx.x, tid = threadIdx.x;
    const int t0 = tc * 125;
    float4_t s = (float4_t){0.f, 0.f, 0.f, 0.f};
    const float4_t* ep = (const float4_t*)(enc + (size_t)b * T_LEN * KDIM) + tid;
    const float* ap = attn + b * T_LEN + t0;
#pragma unroll 5
    for (int tt = 0; tt < 125; ++tt) {
        const float w = ap[tt];
        float4_t v = ep[(size_t)(t0 + tt) * 256];
        s += v * w;
    }
    *(float4_t*)&cpart[(size_t)(tc * BATCH + b) * KDIM + tid * 4] = s;
}

/* out_c[b][o] = b_o[o] + sum_d (sum_p cpart[p][b][d]) * W_o[d][o] ; grid (32,4) x 256 */
__global__ __launch_bounds__(256) void k_out(const float* __restrict__ cpart,
                                             const float* __restrict__ W_o,
                                             const float* __restrict__ b_o,
                                             float* __restrict__ out_c) {
    __shared__ float cm[KDIM];
    const int b = blockIdx.x, tid = threadIdx.x;
    for (int d = tid; d < KDIM; d += 256) {
        float s = 0.f;
#pragma unroll
        for (int p = 0; p < 16; ++p) s += cpart[(size_t)(p * BATCH + b) * KDIM + d];
        cm[d] = s;
    }
    __syncthreads();
    const int o = blockIdx.y * 256 + tid;
    float s = b_o[o];
#pragma unroll 8
    for (int d = 0; d < KDIM; ++d) s += cm[d] * W_o[(size_t)d * KDIM + o];
    out_c[b * KDIM + o] = s;
}

extern "C" void kernel_launch(void* const* d_in, const int* in_sizes, int n_in,
                              void* d_out, int out_size, void* d_ws, size_t ws_size,
                              hipStream_t stream) {
    const float* enc      = (const float*)d_in[0];
    const int*   enc_len  = (const int*)d_in[1];
    const float* dec_h    = (const float*)d_in[2];
    const float* att_prev = (const float*)d_in[3];
    const float* W_enc    = (const float*)d_in[4];
    const float* b_enc    = (const float*)d_in[5];
    const float* W_dec    = (const float*)d_in[6];
    const float* b_dec    = (const float*)d_in[7];
    const float* W_att    = (const float*)d_in[8];
    const float* b_att    = (const float*)d_in[9];
    const float* conv_w   = (const float*)d_in[10];
    const float* gvec     = (const float*)d_in[11];
    const float* W_o      = (const float*)d_in[12];
    const float* b_o      = (const float*)d_in[13];

    float* out_c    = (float*)d_out;           /* 32*1024 */
    float* out_attn = out_c + BATCH * KDIM;    /* 32*2000 */

    char* ws = (char*)d_ws;
    _Float16* Wet   = (_Float16*)(ws + OFF_WENCT);
    _Float16* Wat   = (_Float16*)(ws + OFF_WATTT);
    _Float16* convA = (_Float16*)(ws + OFF_CONVA);
    float*    dterm = (float*)(ws + OFF_DTERM);
    float*    epart = (float*)(ws + OFF_EPART);
    float*    cpart = (float*)(ws + OFF_CPART);

    k_prep_we<<<dim3(32, 16), 256, 0, stream>>>(W_enc, Wet);
    k_prep_wat<<<1, 512, 0, stream>>>(W_att, Wat);
    k_dterm<<<dim3(BATCH, 4), 256, 0, stream>>>(dec_h, W_dec, b_enc, b_dec, b_att, dterm);
    k_conv<<<dim3(16, BATCH), 256, 0, stream>>>(att_prev, conv_w, convA);
    k_gemm_e<<<500, 512, 0, stream>>>(enc, Wet, convA, Wat, dterm, gvec, epart);
    k_softmax<<<BATCH, 512, 0, stream>>>(epart, enc_len, out_attn);
    k_cpart<<<dim3(16, BATCH), 256, 0, stream>>>(out_attn, enc, cpart);
    k_out<<<dim3(BATCH, 4), 256, 0, stream>>>(cpart, W_o, b_o, out_c);
}